// Round 1
// baseline (101.166 us; speedup 1.0000x reference)
//
#include <hip/hip_runtime.h>
#include <hip/hip_bf16.h>

typedef __bf16 bf16x8 __attribute__((ext_vector_type(8)));
typedef float  f32x4  __attribute__((ext_vector_type(4)));

#define N_ROWS 65536
#define N_CLU  1024
#define N_F    512

__device__ __forceinline__ void gload_lds16(const void* g, void* l) {
  __builtin_amdgcn_global_load_lds(
      (const __attribute__((address_space(1))) void*)g,
      (__attribute__((address_space(3))) void*)l, 16, 0, 0);
}

// ---- kernel 1: L2-normalize m rows, store bf16 row-major [1024][512] ----
__global__ __launch_bounds__(256) void knorm_m(const float* __restrict__ m,
                                               __bf16* __restrict__ mn) {
  const int wave = threadIdx.x >> 6, lane = threadIdx.x & 63;
  const int row = blockIdx.x * 4 + wave;
  const float* p = m + (size_t)row * N_F + lane * 8;
  float4 a = ((const float4*)p)[0];
  float4 b = ((const float4*)p)[1];
  float ss = a.x*a.x + a.y*a.y + a.z*a.z + a.w*a.w
           + b.x*b.x + b.y*b.y + b.z*b.z + b.w*b.w;
#pragma unroll
  for (int off = 1; off < 64; off <<= 1) ss += __shfl_xor(ss, off);
  const float inv = 1.0f / fmaxf(sqrtf(ss), 1e-12f);
  bf16x8 o;
  o[0] = (__bf16)(a.x*inv); o[1] = (__bf16)(a.y*inv);
  o[2] = (__bf16)(a.z*inv); o[3] = (__bf16)(a.w*inv);
  o[4] = (__bf16)(b.x*inv); o[5] = (__bf16)(b.y*inv);
  o[6] = (__bf16)(b.z*inv); o[7] = (__bf16)(b.w*inv);
  *(bf16x8*)(mn + (size_t)row * N_F + lane * 8) = o;
}

// ---- kernel 2: fused normalize(x) @ mn^T -> softmax-entropy partial sums ----
// block = 256 thr (4 waves). wave owns 32 x-rows in registers.
// m streamed via double-buffered LDS tiles of 32 clusters.
__global__ __launch_bounds__(256, 2) void kmain(const float* __restrict__ x,
                                                const __bf16* __restrict__ mn,
                                                float* __restrict__ acc_out) {
  __shared__ __align__(16) __bf16 mbuf[2][32][520];   // +8 elem pad per row
  const int tid = threadIdx.x, wave = tid >> 6, lane = tid & 63;
  const int r16 = lane & 15, g = lane >> 4;

  // stage cluster tile 0 (each wave stages 8 rows)
#pragma unroll
  for (int k = 0; k < 8; ++k) {
    const int r = wave * 8 + k;
    gload_lds16((const char*)mn + (size_t)r * (N_F * 2) + lane * 16,
                &mbuf[0][r][0]);
  }

  // load + normalize this wave's 32 x-rows into B-fragments (registers)
  bf16x8 xf0[16], xf1[16];
  const int row0 = blockIdx.x * 128 + wave * 32;
  {
    const float* p0 = x + (size_t)(row0 + r16) * N_F + g * 8;
    float ss = 0.f;
#pragma unroll
    for (int i = 0; i < 16; ++i) {
      float4 a = *(const float4*)(p0 + i * 32);
      float4 b = *(const float4*)(p0 + i * 32 + 4);
      ss += a.x*a.x + a.y*a.y + a.z*a.z + a.w*a.w
          + b.x*b.x + b.y*b.y + b.z*b.z + b.w*b.w;
      bf16x8 f;
      f[0] = (__bf16)a.x; f[1] = (__bf16)a.y; f[2] = (__bf16)a.z; f[3] = (__bf16)a.w;
      f[4] = (__bf16)b.x; f[5] = (__bf16)b.y; f[6] = (__bf16)b.z; f[7] = (__bf16)b.w;
      xf0[i] = f;
    }
    ss += __shfl_xor(ss, 16); ss += __shfl_xor(ss, 32);
    const float inv = 1.0f / fmaxf(sqrtf(ss), 1e-12f);
#pragma unroll
    for (int i = 0; i < 16; ++i)
#pragma unroll
      for (int j = 0; j < 8; ++j)
        xf0[i][j] = (__bf16)((float)xf0[i][j] * inv);
  }
  {
    const float* p1 = x + (size_t)(row0 + 16 + r16) * N_F + g * 8;
    float ss = 0.f;
#pragma unroll
    for (int i = 0; i < 16; ++i) {
      float4 a = *(const float4*)(p1 + i * 32);
      float4 b = *(const float4*)(p1 + i * 32 + 4);
      ss += a.x*a.x + a.y*a.y + a.z*a.z + a.w*a.w
          + b.x*b.x + b.y*b.y + b.z*b.z + b.w*b.w;
      bf16x8 f;
      f[0] = (__bf16)a.x; f[1] = (__bf16)a.y; f[2] = (__bf16)a.z; f[3] = (__bf16)a.w;
      f[4] = (__bf16)b.x; f[5] = (__bf16)b.y; f[6] = (__bf16)b.z; f[7] = (__bf16)b.w;
      xf1[i] = f;
    }
    ss += __shfl_xor(ss, 16); ss += __shfl_xor(ss, 32);
    const float inv = 1.0f / fmaxf(sqrtf(ss), 1e-12f);
#pragma unroll
    for (int i = 0; i < 16; ++i)
#pragma unroll
      for (int j = 0; j < 8; ++j)
        xf1[i][j] = (__bf16)((float)xf1[i][j] * inv);
  }

  float L0 = 0.f, L1 = 0.f, S0 = 0.f, S1 = 0.f;
  __syncthreads();   // drains vmcnt(0) -> tile 0 staged

  for (int t = 0; t < 32; ++t) {
    const int cur = t & 1;
    if (t < 31) {   // prefetch next tile into other buffer
#pragma unroll
      for (int k = 0; k < 8; ++k) {
        const int r = wave * 8 + k;
        const int c = (t + 1) * 32 + r;
        gload_lds16((const char*)mn + (size_t)c * (N_F * 2) + lane * 16,
                    &mbuf[cur ^ 1][r][0]);
      }
    }
    f32x4 a00 = {0,0,0,0}, a01 = {0,0,0,0}, a10 = {0,0,0,0}, a11 = {0,0,0,0};
    const __bf16* mb0 = &mbuf[cur][r16][g * 8];
    const __bf16* mb1 = &mbuf[cur][16 + r16][g * 8];
#pragma unroll
    for (int i = 0; i < 16; ++i) {
      bf16x8 a0 = *(const bf16x8*)(mb0 + i * 32);
      bf16x8 a1 = *(const bf16x8*)(mb1 + i * 32);
      a00 = __builtin_amdgcn_mfma_f32_16x16x32_bf16(a0, xf0[i], a00, 0, 0, 0);
      a01 = __builtin_amdgcn_mfma_f32_16x16x32_bf16(a0, xf1[i], a01, 0, 0, 0);
      a10 = __builtin_amdgcn_mfma_f32_16x16x32_bf16(a1, xf0[i], a10, 0, 0, 0);
      a11 = __builtin_amdgcn_mfma_f32_16x16x32_bf16(a1, xf1[i], a11, 0, 0, 0);
    }
    // fused entropy partials: no max needed, y in [-1,1]
#pragma unroll
    for (int r = 0; r < 4; ++r) {
      { float y = a00[r]; float e = __expf(y); L0 += e; S0 = fmaf(e, y, S0); }
      { float y = a10[r]; float e = __expf(y); L0 += e; S0 = fmaf(e, y, S0); }
      { float y = a01[r]; float e = __expf(y); L1 += e; S1 = fmaf(e, y, S1); }
      { float y = a11[r]; float e = __expf(y); L1 += e; S1 = fmaf(e, y, S1); }
    }
    __syncthreads();   // drains staging vmcnt + LDS reads before buffer reuse
  }

  // finish: combine the 4 lane-groups (disjoint cluster subsets per row)
  float h = 0.f;
  {
    float L = L0; L += __shfl_xor(L, 16); L += __shfl_xor(L, 32);
    float S = S0; S += __shfl_xor(S, 16); S += __shfl_xor(S, 32);
    h += __logf(L) - S / L;
  }
  {
    float L = L1; L += __shfl_xor(L, 16); L += __shfl_xor(L, 32);
    float S = S1; S += __shfl_xor(S, 16); S += __shfl_xor(S, 32);
    h += __logf(L) - S / L;
  }
  h *= 0.25f;   // each row replicated across 4 lanes
#pragma unroll
  for (int off = 1; off < 64; off <<= 1) h += __shfl_xor(h, off);
  if (lane == 0) atomicAdd(acc_out, h);
}

// ---- kernel 3: finalize ----
__global__ void kfin(const float* __restrict__ acc, float* __restrict__ out) {
  const float mean = acc[0] * (1.0f / (float)N_ROWS);
  out[0] = mean;   // total
  out[1] = mean;   // intra
  out[2] = 0.0f;   // inter
}

extern "C" void kernel_launch(void* const* d_in, const int* in_sizes, int n_in,
                              void* d_out, int out_size, void* d_ws, size_t ws_size,
                              hipStream_t stream) {
  const float* x = (const float*)d_in[0];
  const float* m = (const float*)d_in[1];
  float* acc = (float*)d_ws;
  __bf16* mn = (__bf16*)((char*)d_ws + 64);

  hipMemsetAsync(d_ws, 0, 64, stream);
  knorm_m<<<256, 256, 0, stream>>>(m, mn);
  kmain<<<512, 256, 0, stream>>>(x, mn, acc);
  kfin<<<1, 1, 0, stream>>>(acc, (float*)d_out);
}

// Round 3
// 98.894 us; speedup vs baseline: 1.0230x; 1.0230x over previous
//
#include <hip/hip_runtime.h>
#include <hip/hip_bf16.h>

typedef float  f32x4  __attribute__((ext_vector_type(4)));
typedef unsigned long long u64;

#define N_ROWS 65536
#define N_F    512
#define N_CLU  1024

template <bool HI>
static __device__ __forceinline__ unsigned pk8(float a, float b, unsigned old) {
  return (unsigned)__builtin_amdgcn_cvt_pk_fp8_f32(a, b, (int)old, HI);
}

// ---- kernel 1: L2-normalize m rows, store fp8-e4m3 row-major [1024][512] ----
__global__ __launch_bounds__(256) void knorm_m(const float* __restrict__ m,
                                               uint2* __restrict__ mn) {
  const int wave = threadIdx.x >> 6, lane = threadIdx.x & 63;
  const int row = blockIdx.x * 4 + wave;
  const float* p = m + (size_t)row * N_F + lane * 8;
  float4 a = ((const float4*)p)[0];
  float4 b = ((const float4*)p)[1];
  float ss = a.x*a.x + a.y*a.y + a.z*a.z + a.w*a.w
           + b.x*b.x + b.y*b.y + b.z*b.z + b.w*b.w;
#pragma unroll
  for (int off = 1; off < 64; off <<= 1) ss += __shfl_xor(ss, off);
  const float inv = 1.0f / fmaxf(sqrtf(ss), 1e-12f);
  unsigned lo = pk8<false>(a.x*inv, a.y*inv, 0u);
  lo = pk8<true>(a.z*inv, a.w*inv, lo);
  unsigned hi = pk8<false>(b.x*inv, b.y*inv, 0u);
  hi = pk8<true>(b.z*inv, b.w*inv, hi);
  mn[(size_t)row * 64 + lane] = make_uint2(lo, hi);
}

// ---- kernel 2: fused normalize(x) @ mn^T (fp8 MFMA) -> entropy partials ----
// 4 waves/block, wave owns 32 x-rows in fp8 registers; m streamed through
// 3-buffer XOR-swizzled LDS tiles of 32 clusters; raw s_barrier (lgkm-only
// drain) so prefetch global loads stay in flight across barriers.
__global__ __launch_bounds__(256, 2) void kmain(const float* __restrict__ x,
                                                const u64* __restrict__ mn8,
                                                float* __restrict__ acc_out) {
  __shared__ u64 mbuf[3][32][64];   // 48 KiB: 3 bufs x 32 rows x 512B
  const int tid = threadIdx.x, wave = tid >> 6, lane = tid & 63;
  const int r16 = lane & 15, g = lane >> 4;

  long xb0[16], xb1[16];
  float L0 = 0.f, S0 = 0.f, L1 = 0.f, S1 = 0.f;

  auto loadset = [&](u64* s, int t) {
    const char* base = (const char*)mn8 + ((size_t)(t * 32 + wave * 8) << 9) + lane * 8;
#pragma unroll
    for (int k = 0; k < 8; ++k) s[k] = *(const u64*)(base + (k << 9));
  };
  const int lxw = lane ^ ((wave & 1) << 3);
  auto writeset = [&](const u64* s, int t) {
    char* dst = (char*)&mbuf[t % 3][wave * 8][0];
#pragma unroll
    for (int k = 0; k < 8; ++k)
      *(u64*)(dst + (k << 9) + ((lxw ^ k) << 3)) = s[k];
  };

  // swizzled read offsets: logical 8B-unit (4i|g) at physical (4i|g)^r16
  const int swzhi = (r16 & 12) << 3;
  const int boff0 = (r16 << 9) + ((g ^ (r16 & 3)) << 3);

  auto tile = [&](int t) {
    const char* mb = (const char*)&mbuf[t % 3][0][0];
    const char* b0 = mb + boff0;
    const char* b1 = b0 + (16 << 9);
    f32x4 a00 = {0.f,0.f,0.f,0.f}, a01 = {0.f,0.f,0.f,0.f};
    f32x4 a10 = {0.f,0.f,0.f,0.f}, a11 = {0.f,0.f,0.f,0.f};
#pragma unroll
    for (int i = 0; i < 16; ++i) {
      const int off = (i << 5) ^ swzhi;
      long a0 = *(const long*)(b0 + off);
      long a1 = *(const long*)(b1 + off);
      a00 = __builtin_amdgcn_mfma_f32_16x16x32_fp8_fp8(a0, xb0[i], a00, 0, 0, 0);
      a01 = __builtin_amdgcn_mfma_f32_16x16x32_fp8_fp8(a0, xb1[i], a01, 0, 0, 0);
      a10 = __builtin_amdgcn_mfma_f32_16x16x32_fp8_fp8(a1, xb0[i], a10, 0, 0, 0);
      a11 = __builtin_amdgcn_mfma_f32_16x16x32_fp8_fp8(a1, xb1[i], a11, 0, 0, 0);
    }
#pragma unroll
    for (int r = 0; r < 4; ++r) {
      { float y = a00[r]; float e = __expf(y); L0 += e; S0 = fmaf(e, y, S0); }
      { float y = a10[r]; float e = __expf(y); L0 += e; S0 = fmaf(e, y, S0); }
      { float y = a01[r]; float e = __expf(y); L1 += e; S1 = fmaf(e, y, S1); }
      { float y = a11[r]; float e = __expf(y); L1 += e; S1 = fmaf(e, y, S1); }
    }
  };

  u64 sA[8], sB[8];
  loadset(sA, 0);    // issue staging loads first; x prologue hides latency
  loadset(sB, 1);

  // ---- x prologue, two-pass: pass 1 = sum of squares ----
  const int row0 = blockIdx.x * 128 + wave * 32;
  const float* px0 = x + (size_t)(row0 + r16) * N_F + g * 8;
  const float* px1 = x + (size_t)(row0 + 16 + r16) * N_F + g * 8;
  float ss0 = 0.f, ss1 = 0.f;
#pragma unroll
  for (int i = 0; i < 16; ++i) {
    float4 a = *(const float4*)(px0 + i * 32);
    float4 b = *(const float4*)(px0 + i * 32 + 4);
    ss0 += a.x*a.x + a.y*a.y + a.z*a.z + a.w*a.w
         + b.x*b.x + b.y*b.y + b.z*b.z + b.w*b.w;
    float4 c = *(const float4*)(px1 + i * 32);
    float4 d = *(const float4*)(px1 + i * 32 + 4);
    ss1 += c.x*c.x + c.y*c.y + c.z*c.z + c.w*c.w
         + d.x*d.x + d.y*d.y + d.z*d.z + d.w*d.w;
  }
  ss0 += __shfl_xor(ss0, 16); ss0 += __shfl_xor(ss0, 32);
  ss1 += __shfl_xor(ss1, 16); ss1 += __shfl_xor(ss1, 32);
  const float inv0 = 1.0f / fmaxf(sqrtf(ss0), 1e-12f);
  const float inv1 = 1.0f / fmaxf(sqrtf(ss1), 1e-12f);

  // pass 2: reload (L1/L2-hot) and pack normalized fp8 B-fragments
#pragma unroll
  for (int i = 0; i < 16; ++i) {
    float4 a = *(const float4*)(px0 + i * 32);
    float4 b = *(const float4*)(px0 + i * 32 + 4);
    unsigned lo = pk8<false>(a.x*inv0, a.y*inv0, 0u);
    lo = pk8<true>(a.z*inv0, a.w*inv0, lo);
    unsigned hi = pk8<false>(b.x*inv0, b.y*inv0, 0u);
    hi = pk8<true>(b.z*inv0, b.w*inv0, hi);
    xb0[i] = (long)(((u64)hi << 32) | lo);
    float4 c = *(const float4*)(px1 + i * 32);
    float4 d = *(const float4*)(px1 + i * 32 + 4);
    unsigned lo1 = pk8<false>(c.x*inv1, c.y*inv1, 0u);
    lo1 = pk8<true>(c.z*inv1, c.w*inv1, lo1);
    unsigned hi1 = pk8<false>(d.x*inv1, d.y*inv1, 0u);
    hi1 = pk8<true>(d.z*inv1, d.w*inv1, hi1);
    xb1[i] = (long)(((u64)hi1 << 32) | lo1);
  }

  writeset(sA, 0);
  writeset(sB, 1);
  loadset(sA, 2);
  asm volatile("s_waitcnt lgkmcnt(0)" ::: "memory");
  __builtin_amdgcn_s_barrier();

#pragma unroll 1
  for (int t = 0; t < 32; t += 2) {
    // even tile t
    if (t + 2 < 32) writeset(sA, t + 2);
    if (t + 3 < 32) loadset(sB, t + 3);
    tile(t);
    asm volatile("s_waitcnt lgkmcnt(0)" ::: "memory");
    __builtin_amdgcn_s_barrier();
    // odd tile t+1
    if (t + 3 < 32) writeset(sB, t + 3);
    if (t + 4 < 32) loadset(sA, t + 4);
    tile(t + 1);
    asm volatile("s_waitcnt lgkmcnt(0)" ::: "memory");
    __builtin_amdgcn_s_barrier();
  }

  // ---- finish: combine 4 lane-groups (disjoint cluster subsets per row) ----
  float h = 0.f;
  {
    float L = L0; L += __shfl_xor(L, 16); L += __shfl_xor(L, 32);
    float S = S0; S += __shfl_xor(S, 16); S += __shfl_xor(S, 32);
    h += __logf(L) - S / L;
  }
  {
    float L = L1; L += __shfl_xor(L, 16); L += __shfl_xor(L, 32);
    float S = S1; S += __shfl_xor(S, 16); S += __shfl_xor(S, 32);
    h += __logf(L) - S / L;
  }
  h *= 0.25f;   // each row replicated across 4 lanes
#pragma unroll
  for (int off = 1; off < 64; off <<= 1) h += __shfl_xor(h, off);
  if (lane == 0) atomicAdd(acc_out, h);
}

// ---- kernel 3: finalize ----
__global__ void kfin(const float* __restrict__ acc, float* __restrict__ out) {
  const float mean = acc[0] * (1.0f / (float)N_ROWS);
  out[0] = mean;   // total
  out[1] = mean;   // intra
  out[2] = 0.0f;   // inter
}

extern "C" void kernel_launch(void* const* d_in, const int* in_sizes, int n_in,
                              void* d_out, int out_size, void* d_ws, size_t ws_size,
                              hipStream_t stream) {
  const float* x = (const float*)d_in[0];
  const float* m = (const float*)d_in[1];
  float* acc = (float*)d_ws;
  uint2* mn = (uint2*)((char*)d_ws + 64);

  (void)hipMemsetAsync(d_ws, 0, 64, stream);
  knorm_m<<<256, 256, 0, stream>>>(m, mn);
  kmain<<<512, 256, 0, stream>>>(x, (const u64*)mn, acc);
  kfin<<<1, 1, 0, stream>>>(acc, (float*)d_out);
}